// Round 7
// baseline (489.278 us; speedup 1.0000x reference)
//
#include <hip/hip_runtime.h>
#include <math.h>

#define EMB 8
#define SEQ 1024
#define NBATCH 32
#define NROWS (NBATCH * SEQ)
#define LNEPS 1e-5f

typedef __attribute__((ext_vector_type(8))) short bf16x8;
typedef __attribute__((ext_vector_type(16))) float f32x16;

union FragU { unsigned u[4]; bf16x8 s; };

__device__ __forceinline__ unsigned cvt_pk_bf16(float lo, float hi) {
    unsigned r;
    asm("v_cvt_pk_bf16_f32 %0, %1, %2" : "=v"(r) : "v"(lo), "v"(hi));
    return r;
}
__device__ __forceinline__ float bfu_lo(unsigned p) { return __uint_as_float(p << 16); }
__device__ __forceinline__ float bfu_hi(unsigned p) { return __uint_as_float(p & 0xFFFF0000u); }

// Closed-form quantum head: RX layer + Clifford (CNOT chain + H) conjugates
// each Z_i into a product of cos(x_j) (even/odd prefix products).
__device__ __forceinline__ void qhead(const float xv[8], float z[8]) {
    float c[8];
#pragma unroll
    for (int j = 0; j < 8; ++j) c[j] = __cosf(xv[j]);
    float e0 = c[0];
    float o1 = c[1];
    float e2 = e0 * c[2];
    float o3 = o1 * c[3];
    float e4 = e2 * c[4];
    float o5 = o3 * c[5];
    float e6 = e4 * c[6];
    z[0] = e0; z[1] = o1; z[2] = e2; z[3] = o3;
    z[4] = e4; z[5] = o5; z[6] = e6;
    z[7] = e6 * o5 * c[7];
}

// Flags must be zero at kernel start; harness poisons d_ws with 0xAA once and
// never re-poisons, so re-zero on every call (stream-ordered before qt_fused).
__global__ __launch_bounds__(1024) void zero_flags(unsigned* __restrict__ f) {
    for (int i = threadIdx.x; i < 3584; i += 1024) f[i] = 0u;
}

// Whole model in one persistent kernel. Grid 512 = 16 WGs x 32 batches,
// b = bid&31 so a batch's 16 WGs land on one XCD (round-robin dispatch).
// 70.4 KB LDS + launch_bounds(256,2) => exactly 2 WG/CU => all 512 WGs
// co-resident => batch-scoped flag spin cannot deadlock.
// Per layer: arrive cnt[l][b] (release) after qkv writes; spin to 16 +
// acquire fence before staging. x lives in wave-0 registers end-to-end.
__global__ __launch_bounds__(256, 2) void qt_fused(
    const int* __restrict__ tokens, const float* __restrict__ emb,
    const float* __restrict__ attn_w, const float* __restrict__ attn_b,
    const float* __restrict__ ln1_g, const float* __restrict__ ln1_b,
    const float* __restrict__ ffn_w1, const float* __restrict__ ffn_b1,
    const float* __restrict__ ffn_w2, const float* __restrict__ ffn_b2,
    const float* __restrict__ ln2_g, const float* __restrict__ ln2_b,
    const float* __restrict__ cls_w, const float* __restrict__ cls_b,
    float* __restrict__ qkv, unsigned* __restrict__ cnt,
    unsigned* __restrict__ pcnt, float* __restrict__ partial,
    float* __restrict__ out)
{
    __shared__ unsigned short KbH[SEQ * 8];      // 16 KB bf16(beta*z)
    __shared__ unsigned short KbL[SEQ * 8];      // 16 KB bf16 residual
    __shared__ unsigned short VtH[8][1032];      // bf16(z) transposed
    __shared__ unsigned short VtL[8][1032];      // residual, transposed
    __shared__ float Olds[4][32][9];             // per-wave PV partials
    __shared__ int isLast;

    const int bid = blockIdx.x;
    const int b = bid & 31;          // batch: 16 WGs of b share an XCD
    const int wgx = bid >> 5;        // 64-row chunk within batch
    const int tid = threadIdx.x;
    const float beta = 0.71423162f;  // sqrt(log2(e)/sqrt(8))

    const int w = tid >> 6;
    const int lane = tid & 63;
    const int ln = lane & 31;
    const int h = lane >> 5;
    const int qbase = wgx * 64 + (w >> 1) * 32;
    const int khalf = w & 1;
    const long mygrow = (long)b * SEQ + wgx * 64 + tid;   // tid<64 row

    // ---------------- embed + posenc + first qhead (own 64 rows) ----------
    float xv[8];
    if (tid < 64) {
        const int myrow = wgx * 64 + tid;
        int tok = tokens[mygrow];
        const float* e = emb + (long)tok * EMB;
        float p = (float)myrow;
        xv[0] = e[0] + sinf(p);
        xv[1] = e[1] + cosf(p);
        xv[2] = e[2] + sinf(p * 0.1f);
        xv[3] = e[3] + cosf(p * 0.1f);
        xv[4] = e[4] + sinf(p * 0.01f);
        xv[5] = e[5] + cosf(p * 0.01f);
        xv[6] = e[6] + sinf(p * 0.001f);
        xv[7] = e[7] + cosf(p * 0.001f);
        float z[8]; qhead(xv, z);
        float4* qo = (float4*)(qkv + mygrow * 8);
        qo[0] = make_float4(z[0], z[1], z[2], z[3]);
        qo[1] = make_float4(z[4], z[5], z[6], z[7]);
    }
    __threadfence();                               // release qkv writes
    if (tid == 0)
        __hip_atomic_fetch_add(&cnt[(0 * 32 + b) * 16], 1u,
                               __ATOMIC_RELEASE, __HIP_MEMORY_SCOPE_AGENT);

    for (int l = 0; l < 6; ++l) {
        // ---- wait for all 16 WGs of this batch to publish layer-l qkv ----
        if (tid == 0) {
            while (__hip_atomic_load(&cnt[(l * 32 + b) * 16],
                                     __ATOMIC_RELAXED, __HIP_MEMORY_SCOPE_AGENT) < 16u)
                __builtin_amdgcn_s_sleep(2);
        }
        __syncthreads();
        __threadfence();                           // acquire: invalidate caches

        // ---- stage qkv -> KbH/KbL, VtH/VtL ----
        {
            const float* src = qkv + (long)b * SEQ * EMB;
            const int k0 = tid * 4;
            float v[4][8];
#pragma unroll
            for (int i = 0; i < 4; ++i) {
                float4 a0 = *(const float4*)(src + (long)(k0 + i) * 8);
                float4 a1 = *(const float4*)(src + (long)(k0 + i) * 8 + 4);
                v[i][0] = a0.x; v[i][1] = a0.y; v[i][2] = a0.z; v[i][3] = a0.w;
                v[i][4] = a1.x; v[i][5] = a1.y; v[i][6] = a1.z; v[i][7] = a1.w;
            }
#pragma unroll
            for (int i = 0; i < 4; ++i) {
                float bv[8];
#pragma unroll
                for (int c = 0; c < 8; ++c) bv[c] = v[i][c] * beta;
                unsigned ph[4], pl[4];
#pragma unroll
                for (int d = 0; d < 4; ++d) {
                    ph[d] = cvt_pk_bf16(bv[2 * d], bv[2 * d + 1]);
                    float l0 = bv[2 * d] - bfu_lo(ph[d]);
                    float l1 = bv[2 * d + 1] - bfu_hi(ph[d]);
                    pl[d] = cvt_pk_bf16(l0, l1);
                }
                unsigned* dh = (unsigned*)&KbH[(k0 + i) * 8];
                unsigned* dl = (unsigned*)&KbL[(k0 + i) * 8];
#pragma unroll
                for (int d = 0; d < 4; ++d) { dh[d] = ph[d]; dl[d] = pl[d]; }
            }
#pragma unroll
            for (int c = 0; c < 8; ++c) {
                unsigned h0 = cvt_pk_bf16(v[0][c], v[1][c]);
                unsigned h1 = cvt_pk_bf16(v[2][c], v[3][c]);
                unsigned l0 = cvt_pk_bf16(v[0][c] - bfu_lo(h0), v[1][c] - bfu_hi(h0));
                unsigned l1 = cvt_pk_bf16(v[2][c] - bfu_lo(h1), v[3][c] - bfu_hi(h1));
                unsigned* dh = (unsigned*)&VtH[c][k0];
                unsigned* dl = (unsigned*)&VtL[c][k0];
                dh[0] = h0; dh[1] = h1; dl[0] = l0; dl[1] = l1;
            }
        }
        __syncthreads();

        // ---- MFMA attention (swapped QK^T + hi/lo) ----
        FragU qfB, qfB2;
        {
            const unsigned* qh = (const unsigned*)&KbH[(qbase + ln) * 8 + 4 * h];
            const unsigned* ql = (const unsigned*)&KbL[(qbase + ln) * 8 + 4 * h];
            qfB.u[0] = qh[0]; qfB.u[1] = qh[1]; qfB.u[2] = qh[0]; qfB.u[3] = qh[1];
            qfB2.u[0] = ql[0]; qfB2.u[1] = ql[1]; qfB2.u[2] = 0; qfB2.u[3] = 0;
        }
        f32x16 zc;
#pragma unroll
        for (int i = 0; i < 16; ++i) zc[i] = 0.f;
        f32x16 acc = zc;

        for (int t = 0; t < 16; ++t) {
            const int kbase = (khalf * 16 + t) * 32;
            FragU kfA, kfA2;
            {
                const unsigned* kh = (const unsigned*)&KbH[(kbase + ln) * 8 + 4 * h];
                const unsigned* kl = (const unsigned*)&KbL[(kbase + ln) * 8 + 4 * h];
                kfA.u[0] = kh[0]; kfA.u[1] = kh[1]; kfA.u[2] = kl[0]; kfA.u[3] = kl[1];
                kfA2.u[0] = kh[0]; kfA2.u[1] = kh[1]; kfA2.u[2] = 0; kfA2.u[3] = 0;
            }
            f32x16 s = __builtin_amdgcn_mfma_f32_32x32x16_bf16(kfA2.s, qfB2.s, zc, 0, 0, 0);
            s = __builtin_amdgcn_mfma_f32_32x32x16_bf16(kfA.s, qfB.s, s, 0, 0, 0);
            float p[16];
#pragma unroll
            for (int g = 0; g < 16; ++g) p[g] = exp2f(s[g]);

            FragU a1, a2;
#pragma unroll
            for (int vi = 0; vi < 4; ++vi) {
                a1.u[vi] = cvt_pk_bf16(p[2 * vi], p[2 * vi + 1]);
                a2.u[vi] = cvt_pk_bf16(p[8 + 2 * vi], p[8 + 2 * vi + 1]);
            }
            FragU v1h, v2h, v1l, v2l;
            if (ln < 8) {
                const unsigned* r0 = (const unsigned*)&VtH[ln][kbase + 4 * h];
                const unsigned* r1 = (const unsigned*)&VtH[ln][kbase + 8 + 4 * h];
                const unsigned* r2 = (const unsigned*)&VtH[ln][kbase + 16 + 4 * h];
                const unsigned* r3 = (const unsigned*)&VtH[ln][kbase + 24 + 4 * h];
                v1h.u[0] = r0[0]; v1h.u[1] = r0[1]; v1h.u[2] = r1[0]; v1h.u[3] = r1[1];
                v2h.u[0] = r2[0]; v2h.u[1] = r2[1]; v2h.u[2] = r3[0]; v2h.u[3] = r3[1];
                const unsigned* s0 = (const unsigned*)&VtL[ln][kbase + 4 * h];
                const unsigned* s1 = (const unsigned*)&VtL[ln][kbase + 8 + 4 * h];
                const unsigned* s2 = (const unsigned*)&VtL[ln][kbase + 16 + 4 * h];
                const unsigned* s3 = (const unsigned*)&VtL[ln][kbase + 24 + 4 * h];
                v1l.u[0] = s0[0]; v1l.u[1] = s0[1]; v1l.u[2] = s1[0]; v1l.u[3] = s1[1];
                v2l.u[0] = s2[0]; v2l.u[1] = s2[1]; v2l.u[2] = s3[0]; v2l.u[3] = s3[1];
            } else if (ln == 8) {
#pragma unroll
                for (int i = 0; i < 4; ++i) {
                    v1h.u[i] = 0x3F803F80u; v2h.u[i] = 0x3F803F80u;
                    v1l.u[i] = 0; v2l.u[i] = 0;
                }
            } else {
#pragma unroll
                for (int i = 0; i < 4; ++i) { v1h.u[i] = 0; v2h.u[i] = 0; v1l.u[i] = 0; v2l.u[i] = 0; }
            }
            acc = __builtin_amdgcn_mfma_f32_32x32x16_bf16(a1.s, v1h.s, acc, 0, 0, 0);
            acc = __builtin_amdgcn_mfma_f32_32x32x16_bf16(a2.s, v2h.s, acc, 0, 0, 0);
            acc = __builtin_amdgcn_mfma_f32_32x32x16_bf16(a1.s, v1l.s, acc, 0, 0, 0);
            acc = __builtin_amdgcn_mfma_f32_32x32x16_bf16(a2.s, v2l.s, acc, 0, 0, 0);
        }

        if (ln <= 8) {
#pragma unroll
            for (int g = 0; g < 16; ++g)
                Olds[w][(g & 3) + 8 * (g >> 2) + 4 * h][ln] = acc[g];
        }
        __syncthreads();

        // ---- epilogue: wave 0, one thread per row; x stays in registers ----
        if (tid < 64) {
            const int rr = tid & 31;
            const int w0 = (tid >> 5) * 2;
            float o[9];
#pragma unroll
            for (int c = 0; c < 9; ++c) o[c] = Olds[w0][rr][c] + Olds[w0 + 1][rr][c];
            float inv = 1.0f / o[8];
            float outv[8];
#pragma unroll
            for (int c = 0; c < 8; ++c) outv[c] = o[c] * inv;

            const float* W  = attn_w + l * 64; const float* Wb  = attn_b + l * 8;
            const float* g1 = ln1_g + l * 8;   const float* b1v = ln1_b + l * 8;
            const float* W1 = ffn_w1 + l * 64; const float* c1  = ffn_b1 + l * 8;
            const float* W2 = ffn_w2 + l * 64; const float* c2  = ffn_b2 + l * 8;
            const float* g2 = ln2_g + l * 8;   const float* b2v = ln2_b + l * 8;

            float y[8]; float m = 0.f;
#pragma unroll
            for (int j = 0; j < 8; ++j) {
                float vv = Wb[j];
#pragma unroll
                for (int i = 0; i < 8; ++i) vv += outv[i] * W[i * 8 + j];
                y[j] = xv[j] + vv;
                m += y[j];
            }
            m *= 0.125f;
            float var = 0.f;
#pragma unroll
            for (int j = 0; j < 8; ++j) { float d = y[j] - m; var += d * d; }
            var *= 0.125f;
            float rsg = rsqrtf(var + LNEPS);
            float xn[8];
#pragma unroll
            for (int j = 0; j < 8; ++j) xn[j] = g1[j] * (y[j] - m) * rsg + b1v[j];

            float hh[8];
#pragma unroll
            for (int j = 0; j < 8; ++j) {
                float vv = c1[j];
#pragma unroll
                for (int i = 0; i < 8; ++i) vv += xn[i] * W1[i * 8 + j];
                hh[j] = vv;
            }
            float qff[8]; qhead(hh, qff);
            float m2 = 0.f;
#pragma unroll
            for (int j = 0; j < 8; ++j) {
                float vv = c2[j];
#pragma unroll
                for (int i = 0; i < 8; ++i) vv += qff[i] * W2[i * 8 + j];
                y[j] = xn[j] + vv;
                m2 += y[j];
            }
            m2 *= 0.125f;
            float var2 = 0.f;
#pragma unroll
            for (int j = 0; j < 8; ++j) { float d = y[j] - m2; var2 += d * d; }
            var2 *= 0.125f;
            float rs2 = rsqrtf(var2 + LNEPS);
#pragma unroll
            for (int j = 0; j < 8; ++j) xv[j] = g2[j] * (y[j] - m2) * rs2 + b2v[j];

            if (l < 5) {
                float z[8]; qhead(xv, z);
                float4* qw = (float4*)(qkv + mygrow * 8);
                qw[0] = make_float4(z[0], z[1], z[2], z[3]);
                qw[1] = make_float4(z[4], z[5], z[6], z[7]);
            }
        }
        if (l < 5) {
            __threadfence();                        // release next-layer qkv
            if (tid == 0)
                __hip_atomic_fetch_add(&cnt[((l + 1) * 32 + b) * 16], 1u,
                                       __ATOMIC_RELEASE, __HIP_MEMORY_SCOPE_AGENT);
        }
    }

    // ---------------- pool + classifier (last WG per batch) ----------------
    if (tid < 64) {
        float a[8];
#pragma unroll
        for (int j = 0; j < 8; ++j) {
            a[j] = xv[j];
#pragma unroll
            for (int off = 1; off <= 32; off <<= 1) a[j] += __shfl_xor(a[j], off);
        }
        if (tid < 8) partial[(b * 16 + wgx) * 8 + tid] = a[tid];
    }
    __threadfence();                                // release partial stores
    __syncthreads();
    if (tid == 0) {
        unsigned r = __hip_atomic_fetch_add(&pcnt[b * 16], 1u,
                                            __ATOMIC_ACQ_REL, __HIP_MEMORY_SCOPE_AGENT);
        isLast = (r == 15u);
    }
    __syncthreads();
    if (isLast) {
        __threadfence();                            // acquire partials
        if (tid < 10) {
            float o = cls_b[tid];
#pragma unroll
            for (int j = 0; j < 8; ++j) {
                float pj = 0.f;
#pragma unroll
                for (int g = 0; g < 16; ++g) pj += partial[(b * 16 + g) * 8 + j];
                o += pj * (1.0f / 1024.0f) * cls_w[j * 10 + tid];
            }
            out[b * 10 + tid] = o;
        }
    }
}

extern "C" void kernel_launch(void* const* d_in, const int* in_sizes, int n_in,
                              void* d_out, int out_size, void* d_ws, size_t ws_size,
                              hipStream_t stream) {
    const int*   tokens = (const int*)d_in[0];
    const float* emb    = (const float*)d_in[1];
    const float* ln1_g  = (const float*)d_in[2];
    const float* ln1_b  = (const float*)d_in[3];
    const float* ln2_g  = (const float*)d_in[4];
    const float* ln2_b  = (const float*)d_in[5];
    const float* attn_w = (const float*)d_in[6];
    const float* attn_b = (const float*)d_in[7];
    const float* ffn_w1 = (const float*)d_in[8];
    const float* ffn_b1 = (const float*)d_in[9];
    const float* ffn_w2 = (const float*)d_in[10];
    const float* ffn_b2 = (const float*)d_in[11];
    const float* cls_w  = (const float*)d_in[12];
    const float* cls_b  = (const float*)d_in[13];

    // d_ws layout (words): cnt 6*32*16=3072 | pcnt 32*16=512 | partial 32*16*8
    unsigned* cnt     = (unsigned*)d_ws;
    unsigned* pcnt    = cnt + 3072;
    float*    partial = (float*)(pcnt + 512);
    float*    qkv     = partial + 4096;            // 30720 B offset, 16B aligned
    float*    outp    = (float*)d_out;

    zero_flags<<<1, 1024, 0, stream>>>(cnt);       // zeroes cnt+pcnt (3584 words)
    qt_fused<<<512, 256, 0, stream>>>(
        tokens, emb, attn_w, attn_b, ln1_g, ln1_b,
        ffn_w1, ffn_b1, ffn_w2, ffn_b2, ln2_g, ln2_b,
        cls_w, cls_b, qkv, cnt, pcnt, partial, outp);
}

// Round 8
// 117.498 us; speedup vs baseline: 4.1641x; 4.1641x over previous
//
#include <hip/hip_runtime.h>
#include <math.h>

#define EMB 8
#define SEQ 1024
#define NBATCH 32
#define NROWS (NBATCH * SEQ)
#define LNEPS 1e-5f

typedef __attribute__((ext_vector_type(8))) short bf16x8;
typedef __attribute__((ext_vector_type(16))) float f32x16;

union FragU { unsigned u[4]; bf16x8 s; };

__device__ __forceinline__ unsigned cvt_pk_bf16(float lo, float hi) {
    unsigned r;
    asm("v_cvt_pk_bf16_f32 %0, %1, %2" : "=v"(r) : "v"(lo), "v"(hi));
    return r;
}
__device__ __forceinline__ float bfu_lo(unsigned p) { return __uint_as_float(p << 16); }
__device__ __forceinline__ float bfu_hi(unsigned p) { return __uint_as_float(p & 0xFFFF0000u); }

// Write-through / bypass stores+loads: land at the LLC (coherence point),
// independent of XCD placement; no cache-wide maintenance needed.
__device__ __forceinline__ void sys_store(float* p, float v) {
    asm volatile("global_store_dword %0, %1, off sc0 sc1" :: "v"(p), "v"(v) : "memory");
}
__device__ __forceinline__ float sys_load(const float* p) {
    float r;
    asm volatile("global_load_dword %0, %1, off sc0 sc1\n\ts_waitcnt vmcnt(0)"
                 : "=v"(r) : "v"(p) : "memory");
    return r;
}

// Closed-form quantum head: RX layer + Clifford (CNOT chain + H) conjugates
// each Z_i into a product of cos(x_j) (even/odd prefix products).
__device__ __forceinline__ void qhead(const float xv[8], float z[8]) {
    float c[8];
#pragma unroll
    for (int j = 0; j < 8; ++j) c[j] = __cosf(xv[j]);
    float e0 = c[0];
    float o1 = c[1];
    float e2 = e0 * c[2];
    float o3 = o1 * c[3];
    float e4 = e2 * c[4];
    float o5 = o3 * c[5];
    float e6 = e4 * c[6];
    z[0] = e0; z[1] = o1; z[2] = e2; z[3] = o3;
    z[4] = e4; z[5] = o5; z[6] = e6;
    z[7] = e6 * o5 * c[7];
}

__device__ __forceinline__ void embed_row(const int* __restrict__ tokens,
                                          const float* __restrict__ emb,
                                          long grow, int srow, float xv[8]) {
    int tok = tokens[grow];
    const float* e = emb + (long)tok * EMB;
    float p = (float)srow;
    xv[0] = e[0] + sinf(p);
    xv[1] = e[1] + cosf(p);
    xv[2] = e[2] + sinf(p * 0.1f);
    xv[3] = e[3] + cosf(p * 0.1f);
    xv[4] = e[4] + sinf(p * 0.01f);
    xv[5] = e[5] + cosf(p * 0.01f);
    xv[6] = e[6] + sinf(p * 0.001f);
    xv[7] = e[7] + cosf(p * 0.001f);
}

// One transformer block, MFMA attention (swapped-QK^T + hi/lo precision).
// MODE 0: first layer (embed fused, no x/qkv input); MODE 1: middle;
// MODE 2: last layer (pool+classifier fused, no x/qkv output).
// Kb plane layout KbP[h][row][4 shorts]: staging writes (rows tid+256i) and
// fragment b64 reads are consecutive-8B across lanes -> bank-conflict floor.
template <int MODE>
__global__ __launch_bounds__(256, 2) void layer_kernel(
    const int* __restrict__ tokens, const float* __restrict__ emb,
    float* __restrict__ x, float* __restrict__ qkv,
    const float* __restrict__ W, const float* __restrict__ Wb,
    const float* __restrict__ g1, const float* __restrict__ b1v,
    const float* __restrict__ W1, const float* __restrict__ c1,
    const float* __restrict__ W2, const float* __restrict__ c2,
    const float* __restrict__ g2, const float* __restrict__ b2v,
    const float* __restrict__ cls_w, const float* __restrict__ cls_b,
    unsigned* __restrict__ pcnt, float* __restrict__ partial,
    float* __restrict__ out)
{
    __shared__ __align__(16) unsigned short KbP[2 * SEQ * 4];   // hi planes
    __shared__ __align__(16) unsigned short KbLP[2 * SEQ * 4];  // lo planes
    __shared__ __align__(16) unsigned short VtH[8][1032];
    __shared__ __align__(16) unsigned short VtL[8][1032];
    __shared__ float Olds[4][32][9];
    __shared__ int isLast;

    const int b = blockIdx.y;
    const int wgx = blockIdx.x;
    const int tid = threadIdx.x;
    const float beta = 0.71423162f;   // sqrt(log2(e)/sqrt(8))

    // layer-0 re-zeroes pool counters for the NEXT call/replay chain
    if (MODE == 0 && wgx == 0 && b == 0 && tid < NBATCH) pcnt[tid * 16] = 0u;

    // ---- x for this WG's own 64 rows (registers, wave 0) ----
    float xv[8];
    if (tid < 64) {
        if (MODE == 0) {
            embed_row(tokens, emb, (long)b * SEQ + wgx * 64 + tid, wgx * 64 + tid, xv);
        } else {
            const float4* xp = (const float4*)(x + ((long)b * SEQ + wgx * 64 + tid) * 8);
            float4 x0 = xp[0], x1 = xp[1];
            xv[0] = x0.x; xv[1] = x0.y; xv[2] = x0.z; xv[3] = x0.w;
            xv[4] = x1.x; xv[5] = x1.y; xv[6] = x1.z; xv[7] = x1.w;
        }
    }

    // ---- staging pass K: rows tid+256i -> KbP/KbLP planes ----
#pragma unroll
    for (int i = 0; i < 4; ++i) {
        const int r = tid + (i << 8);
        float z[8];
        if (MODE == 0) {
            float ev[8];
            embed_row(tokens, emb, (long)b * SEQ + r, r, ev);
            qhead(ev, z);
        } else {
            const float4* src = (const float4*)(qkv + ((long)b * SEQ + r) * 8);
            float4 a0 = src[0], a1 = src[1];
            z[0] = a0.x; z[1] = a0.y; z[2] = a0.z; z[3] = a0.w;
            z[4] = a1.x; z[5] = a1.y; z[6] = a1.z; z[7] = a1.w;
        }
        unsigned ph[4], pl[4];
#pragma unroll
        for (int d = 0; d < 4; ++d) {
            float b0 = z[2 * d] * beta, b1 = z[2 * d + 1] * beta;
            ph[d] = cvt_pk_bf16(b0, b1);
            pl[d] = cvt_pk_bf16(b0 - bfu_lo(ph[d]), b1 - bfu_hi(ph[d]));
        }
        uint2 t0; t0.x = ph[0]; t0.y = ph[1];
        uint2 t1; t1.x = ph[2]; t1.y = ph[3];
        uint2 t2; t2.x = pl[0]; t2.y = pl[1];
        uint2 t3; t3.x = pl[2]; t3.y = pl[3];
        *(uint2*)&KbP[r * 4] = t0;
        *(uint2*)&KbP[(SEQ + r) * 4] = t1;
        *(uint2*)&KbLP[r * 4] = t2;
        *(uint2*)&KbLP[(SEQ + r) * 4] = t3;
    }
    // ---- staging pass V: rows 4t..4t+3 -> VtH/VtL (transposed) ----
    {
        const int k0 = tid * 4;
        float v[4][8];
#pragma unroll
        for (int i = 0; i < 4; ++i) {
            if (MODE == 0) {
                float ev[8];
                embed_row(tokens, emb, (long)b * SEQ + k0 + i, k0 + i, ev);
                qhead(ev, v[i]);
            } else {
                const float4* src = (const float4*)(qkv + ((long)b * SEQ + k0 + i) * 8);
                float4 a0 = src[0], a1 = src[1];
                v[i][0] = a0.x; v[i][1] = a0.y; v[i][2] = a0.z; v[i][3] = a0.w;
                v[i][4] = a1.x; v[i][5] = a1.y; v[i][6] = a1.z; v[i][7] = a1.w;
            }
        }
#pragma unroll
        for (int c = 0; c < 8; ++c) {
            unsigned h0 = cvt_pk_bf16(v[0][c], v[1][c]);
            unsigned h1 = cvt_pk_bf16(v[2][c], v[3][c]);
            unsigned l0 = cvt_pk_bf16(v[0][c] - bfu_lo(h0), v[1][c] - bfu_hi(h0));
            unsigned l1 = cvt_pk_bf16(v[2][c] - bfu_lo(h1), v[3][c] - bfu_hi(h1));
            unsigned* dh = (unsigned*)&VtH[c][k0];
            unsigned* dl = (unsigned*)&VtL[c][k0];
            dh[0] = h0; dh[1] = h1; dl[0] = l0; dl[1] = l1;
        }
    }
    __syncthreads();

    const int w = tid >> 6;
    const int lane = tid & 63;
    const int ln = lane & 31;
    const int h = lane >> 5;
    const int qbase = wgx * 64 + (w >> 1) * 32;
    const int khalf = w & 1;

    // Q B-frags (col = ln = this lane's q-row): (q_hi||q_hi), (q_lo||0)
    FragU qfB, qfB2;
    {
        uint2 qh = *(const uint2*)&KbP[(h * SEQ + qbase + ln) * 4];
        uint2 ql = *(const uint2*)&KbLP[(h * SEQ + qbase + ln) * 4];
        qfB.u[0] = qh.x; qfB.u[1] = qh.y; qfB.u[2] = qh.x; qfB.u[3] = qh.y;
        qfB2.u[0] = ql.x; qfB2.u[1] = ql.y; qfB2.u[2] = 0; qfB2.u[3] = 0;
    }

    f32x16 zc;
#pragma unroll
    for (int i = 0; i < 16; ++i) zc[i] = 0.f;
    f32x16 acc = zc;

    for (int t = 0; t < 16; ++t) {
        const int kbase = (khalf * 16 + t) * 32;
        FragU kfA, kfA2;
        {
            uint2 kh = *(const uint2*)&KbP[(h * SEQ + kbase + ln) * 4];
            uint2 kl = *(const uint2*)&KbLP[(h * SEQ + kbase + ln) * 4];
            kfA.u[0] = kh.x; kfA.u[1] = kh.y; kfA.u[2] = kl.x; kfA.u[3] = kl.y;
            kfA2.u[0] = kh.x; kfA2.u[1] = kh.y; kfA2.u[2] = 0; kfA2.u[3] = 0;
        }
        f32x16 s = __builtin_amdgcn_mfma_f32_32x32x16_bf16(kfA2.s, qfB2.s, zc, 0, 0, 0);
        s = __builtin_amdgcn_mfma_f32_32x32x16_bf16(kfA.s, qfB.s, s, 0, 0, 0);
        float p[16];
#pragma unroll
        for (int g = 0; g < 16; ++g) p[g] = exp2f(s[g]);

        FragU a1, a2;
#pragma unroll
        for (int vi = 0; vi < 4; ++vi) {
            a1.u[vi] = cvt_pk_bf16(p[2 * vi], p[2 * vi + 1]);
            a2.u[vi] = cvt_pk_bf16(p[8 + 2 * vi], p[8 + 2 * vi + 1]);
        }
        FragU v1h, v2h, v1l, v2l;
        if (ln < 8) {
            const unsigned* r0 = (const unsigned*)&VtH[ln][kbase + 4 * h];
            const unsigned* r1 = (const unsigned*)&VtH[ln][kbase + 8 + 4 * h];
            const unsigned* r2 = (const unsigned*)&VtH[ln][kbase + 16 + 4 * h];
            const unsigned* r3 = (const unsigned*)&VtH[ln][kbase + 24 + 4 * h];
            v1h.u[0] = r0[0]; v1h.u[1] = r0[1]; v1h.u[2] = r1[0]; v1h.u[3] = r1[1];
            v2h.u[0] = r2[0]; v2h.u[1] = r2[1]; v2h.u[2] = r3[0]; v2h.u[3] = r3[1];
            const unsigned* s0 = (const unsigned*)&VtL[ln][kbase + 4 * h];
            const unsigned* s1 = (const unsigned*)&VtL[ln][kbase + 8 + 4 * h];
            const unsigned* s2 = (const unsigned*)&VtL[ln][kbase + 16 + 4 * h];
            const unsigned* s3 = (const unsigned*)&VtL[ln][kbase + 24 + 4 * h];
            v1l.u[0] = s0[0]; v1l.u[1] = s0[1]; v1l.u[2] = s1[0]; v1l.u[3] = s1[1];
            v2l.u[0] = s2[0]; v2l.u[1] = s2[1]; v2l.u[2] = s3[0]; v2l.u[3] = s3[1];
        } else if (ln == 8) {
#pragma unroll
            for (int i = 0; i < 4; ++i) {
                v1h.u[i] = 0x3F803F80u; v2h.u[i] = 0x3F803F80u;
                v1l.u[i] = 0; v2l.u[i] = 0;
            }
        } else {
#pragma unroll
            for (int i = 0; i < 4; ++i) { v1h.u[i] = 0; v2h.u[i] = 0; v1l.u[i] = 0; v2l.u[i] = 0; }
        }
        acc = __builtin_amdgcn_mfma_f32_32x32x16_bf16(a1.s, v1h.s, acc, 0, 0, 0);
        acc = __builtin_amdgcn_mfma_f32_32x32x16_bf16(a2.s, v2h.s, acc, 0, 0, 0);
        acc = __builtin_amdgcn_mfma_f32_32x32x16_bf16(a1.s, v1l.s, acc, 0, 0, 0);
        acc = __builtin_amdgcn_mfma_f32_32x32x16_bf16(a2.s, v2l.s, acc, 0, 0, 0);
    }

    if (ln <= 8) {
#pragma unroll
        for (int g = 0; g < 16; ++g)
            Olds[w][(g & 3) + 8 * (g >> 2) + 4 * h][ln] = acc[g];
    }
    __syncthreads();

    // ---- epilogue: wave 0, one thread per row ----
    if (tid < 64) {
        const int rr = tid & 31;
        const int w0 = (tid >> 5) * 2;
        float o[9];
#pragma unroll
        for (int c = 0; c < 9; ++c) o[c] = Olds[w0][rr][c] + Olds[w0 + 1][rr][c];
        float inv = 1.0f / o[8];
        float outv[8];
#pragma unroll
        for (int c = 0; c < 8; ++c) outv[c] = o[c] * inv;

        float y[8]; float m = 0.f;
#pragma unroll
        for (int j = 0; j < 8; ++j) {
            float vv = Wb[j];
#pragma unroll
            for (int i = 0; i < 8; ++i) vv += outv[i] * W[i * 8 + j];
            y[j] = xv[j] + vv;
            m += y[j];
        }
        m *= 0.125f;
        float var = 0.f;
#pragma unroll
        for (int j = 0; j < 8; ++j) { float d = y[j] - m; var += d * d; }
        var *= 0.125f;
        float rsg = rsqrtf(var + LNEPS);
        float xn[8];
#pragma unroll
        for (int j = 0; j < 8; ++j) xn[j] = g1[j] * (y[j] - m) * rsg + b1v[j];

        float hh[8];
#pragma unroll
        for (int j = 0; j < 8; ++j) {
            float vv = c1[j];
#pragma unroll
            for (int i = 0; i < 8; ++i) vv += xn[i] * W1[i * 8 + j];
            hh[j] = vv;
        }
        float qff[8]; qhead(hh, qff);
        float m2 = 0.f;
#pragma unroll
        for (int j = 0; j < 8; ++j) {
            float vv = c2[j];
#pragma unroll
            for (int i = 0; i < 8; ++i) vv += qff[i] * W2[i * 8 + j];
            y[j] = xn[j] + vv;
            m2 += y[j];
        }
        m2 *= 0.125f;
        float var2 = 0.f;
#pragma unroll
        for (int j = 0; j < 8; ++j) { float d = y[j] - m2; var2 += d * d; }
        var2 *= 0.125f;
        float rs2 = rsqrtf(var2 + LNEPS);
#pragma unroll
        for (int j = 0; j < 8; ++j) xv[j] = g2[j] * (y[j] - m2) * rs2 + b2v[j];

        if (MODE < 2) {
            const long grow = (long)b * SEQ + wgx * 64 + tid;
            float z[8]; qhead(xv, z);
            float4* xw = (float4*)(x + grow * 8);
            float4* qw = (float4*)(qkv + grow * 8);
            xw[0] = make_float4(xv[0], xv[1], xv[2], xv[3]);
            xw[1] = make_float4(xv[4], xv[5], xv[6], xv[7]);
            qw[0] = make_float4(z[0], z[1], z[2], z[3]);
            qw[1] = make_float4(z[4], z[5], z[6], z[7]);
        }
    }

    // ---- MODE 2: pool + classifier, last-WG-per-batch, fence-free ----
    if (MODE == 2) {
        if (tid < 64) {
            float a[8];
#pragma unroll
            for (int j = 0; j < 8; ++j) {
                a[j] = xv[j];
#pragma unroll
                for (int off = 1; off <= 32; off <<= 1) a[j] += __shfl_xor(a[j], off);
            }
            if (tid < 8) sys_store(&partial[(b * 16 + wgx) * 8 + tid], a[tid]);
        }
        asm volatile("s_waitcnt vmcnt(0)" ::: "memory");
        __syncthreads();
        if (tid == 0) {
            unsigned r = __hip_atomic_fetch_add(&pcnt[b * 16], 1u,
                                                __ATOMIC_RELAXED, __HIP_MEMORY_SCOPE_AGENT);
            isLast = (r == 15u);
        }
        __syncthreads();
        if (isLast && tid < 64) {
            int g = tid >> 3, j = tid & 7;
            float s = sys_load(&partial[(b * 16 + g) * 8 + j])
                    + sys_load(&partial[(b * 16 + g + 8) * 8 + j]);
            s += __shfl_xor(s, 8); s += __shfl_xor(s, 16); s += __shfl_xor(s, 32);
            float poolj = s * (1.0f / 1024.0f);   // lane (g,j): total for feature j
            int c = tid < 10 ? tid : 9;
            float o = cls_b[c];
#pragma unroll
            for (int j2 = 0; j2 < 8; ++j2)
                o += __shfl(poolj, j2) * cls_w[j2 * 10 + c];
            if (tid < 10) out[b * 10 + tid] = o;
        }
    }
}

extern "C" void kernel_launch(void* const* d_in, const int* in_sizes, int n_in,
                              void* d_out, int out_size, void* d_ws, size_t ws_size,
                              hipStream_t stream) {
    const int*   tokens = (const int*)d_in[0];
    const float* emb    = (const float*)d_in[1];
    const float* ln1_g  = (const float*)d_in[2];
    const float* ln1_b  = (const float*)d_in[3];
    const float* ln2_g  = (const float*)d_in[4];
    const float* ln2_b  = (const float*)d_in[5];
    const float* attn_w = (const float*)d_in[6];
    const float* attn_b = (const float*)d_in[7];
    const float* ffn_w1 = (const float*)d_in[8];
    const float* ffn_b1 = (const float*)d_in[9];
    const float* ffn_w2 = (const float*)d_in[10];
    const float* ffn_b2 = (const float*)d_in[11];
    const float* cls_w  = (const float*)d_in[12];
    const float* cls_b  = (const float*)d_in[13];

    // ws layout (f32 words): pcnt 512 | partial 4096 | x 1M | qkv 1M
    unsigned* pcnt    = (unsigned*)d_ws;
    float*    partial = (float*)d_ws + 512;
    float*    x       = (float*)d_ws + 512 + 4096;
    float*    qkv     = x + (long)NROWS * 8;
    float*    outp    = (float*)d_out;

#define ARGS(l) tokens, emb, x, qkv, \
        attn_w + (l) * 64, attn_b + (l) * 8, ln1_g + (l) * 8, ln1_b + (l) * 8, \
        ffn_w1 + (l) * 64, ffn_b1 + (l) * 8, ffn_w2 + (l) * 64, ffn_b2 + (l) * 8, \
        ln2_g + (l) * 8, ln2_b + (l) * 8, cls_w, cls_b, pcnt, partial, outp

    layer_kernel<0><<<dim3(16, NBATCH), 256, 0, stream>>>(ARGS(0));
    for (int l = 1; l < 5; ++l)
        layer_kernel<1><<<dim3(16, NBATCH), 256, 0, stream>>>(ARGS(l));
    layer_kernel<2><<<dim3(16, NBATCH), 256, 0, stream>>>(ARGS(5));
#undef ARGS
}

// Round 9
// 110.135 us; speedup vs baseline: 4.4425x; 1.0669x over previous
//
#include <hip/hip_runtime.h>
#include <math.h>

#define EMB 8
#define SEQ 1024
#define NBATCH 32
#define NROWS (NBATCH * SEQ)
#define LNEPS 1e-5f
#define FL(l, b) (((l) * 32 + (b)) * 16)

typedef __attribute__((ext_vector_type(4))) float f32x4;
typedef __attribute__((ext_vector_type(8))) short bf16x8;
typedef __attribute__((ext_vector_type(16))) float f32x16;

union FragU { unsigned u[4]; bf16x8 s; };

__device__ __forceinline__ unsigned cvt_pk_bf16(float lo, float hi) {
    unsigned r;
    asm("v_cvt_pk_bf16_f32 %0, %1, %2" : "=v"(r) : "v"(lo), "v"(hi));
    return r;
}
__device__ __forceinline__ float bfu_lo(unsigned p) { return __uint_as_float(p << 16); }
__device__ __forceinline__ float bfu_hi(unsigned p) { return __uint_as_float(p & 0xFFFF0000u); }

// LLC-coherent (sc0 sc1) accessors: bypass L1/L2, land at the cross-XCD
// coherence point. No cache-wide maintenance ops anywhere (R7's poison).
__device__ __forceinline__ void llc_load_row4(const float* p, f32x4 d[8]) {
    asm volatile(
        "global_load_dwordx4 %0, %[a], off sc0 sc1\n\t"
        "global_load_dwordx4 %1, %[a], off offset:16 sc0 sc1\n\t"
        "global_load_dwordx4 %2, %[a], off offset:32 sc0 sc1\n\t"
        "global_load_dwordx4 %3, %[a], off offset:48 sc0 sc1\n\t"
        "global_load_dwordx4 %4, %[a], off offset:64 sc0 sc1\n\t"
        "global_load_dwordx4 %5, %[a], off offset:80 sc0 sc1\n\t"
        "global_load_dwordx4 %6, %[a], off offset:96 sc0 sc1\n\t"
        "global_load_dwordx4 %7, %[a], off offset:112 sc0 sc1\n\t"
        "s_waitcnt vmcnt(0)"
        : "=&v"(d[0]), "=&v"(d[1]), "=&v"(d[2]), "=&v"(d[3]),
          "=&v"(d[4]), "=&v"(d[5]), "=&v"(d[6]), "=&v"(d[7])
        : [a] "v"(p) : "memory");
}
__device__ __forceinline__ void llc_store_row(float* p, f32x4 a, f32x4 b) {
    asm volatile(
        "global_store_dwordx4 %[a], %[x], off sc0 sc1\n\t"
        "global_store_dwordx4 %[a], %[y], off offset:16 sc0 sc1"
        :: [a] "v"(p), [x] "v"(a), [y] "v"(b) : "memory");
}
__device__ __forceinline__ void sys_store(float* p, float v) {
    asm volatile("global_store_dword %0, %1, off sc0 sc1" :: "v"(p), "v"(v) : "memory");
}
__device__ __forceinline__ float sys_load(const float* p) {
    float r;
    asm volatile("global_load_dword %0, %1, off sc0 sc1\n\ts_waitcnt vmcnt(0)"
                 : "=v"(r) : "v"(p) : "memory");
    return r;
}

// Closed-form quantum head: RX layer + Clifford (CNOT chain + H) conjugates
// each Z_i into a product of cos(x_j) (even/odd prefix products).
__device__ __forceinline__ void qhead(const float xv[8], float z[8]) {
    float c[8];
#pragma unroll
    for (int j = 0; j < 8; ++j) c[j] = __cosf(xv[j]);
    float e0 = c[0];
    float o1 = c[1];
    float e2 = e0 * c[2];
    float o3 = o1 * c[3];
    float e4 = e2 * c[4];
    float o5 = o3 * c[5];
    float e6 = e4 * c[6];
    z[0] = e0; z[1] = o1; z[2] = e2; z[3] = o3;
    z[4] = e4; z[5] = o5; z[6] = e6;
    z[7] = e6 * o5 * c[7];
}

__device__ __forceinline__ void embed_row(const int* __restrict__ tokens,
                                          const float* __restrict__ emb,
                                          long grow, int srow, float xv[8]) {
    int tok = tokens[grow];
    const float* e = emb + (long)tok * EMB;
    float p = (float)srow;
    xv[0] = e[0] + sinf(p);
    xv[1] = e[1] + cosf(p);
    xv[2] = e[2] + sinf(p * 0.1f);
    xv[3] = e[3] + cosf(p * 0.1f);
    xv[4] = e[4] + sinf(p * 0.01f);
    xv[5] = e[5] + cosf(p * 0.01f);
    xv[6] = e[6] + sinf(p * 0.001f);
    xv[7] = e[7] + cosf(p * 0.001f);
}

// Flags must be zero at kernel start each call (harness poisons ws once).
__global__ __launch_bounds__(1024) void zero_flags(unsigned* __restrict__ f) {
    for (int i = threadIdx.x; i < 3584; i += 1024) f[i] = 0u;
}

// Whole model, one persistent kernel. 512 WGs = 16 per batch (b = bid&31 ->
// a batch's WGs share an XCD). 53.9 KB LDS => >=2 WG/CU capacity => all 512
// co-resident. Per-layer batch-scoped sync: sc0sc1 publish + vmcnt(0) +
// relaxed agent atomic arrive; spin to 16; sc0sc1 stage reads. qkv parity
// double-buffered so layer l+1 writes never race layer-l readers.
__global__ __launch_bounds__(256, 2) void qt_fused(
    const int* __restrict__ tokens, const float* __restrict__ emb,
    const float* __restrict__ attn_w, const float* __restrict__ attn_b,
    const float* __restrict__ ln1_g, const float* __restrict__ ln1_b,
    const float* __restrict__ ffn_w1, const float* __restrict__ ffn_b1,
    const float* __restrict__ ffn_w2, const float* __restrict__ ffn_b2,
    const float* __restrict__ ln2_g, const float* __restrict__ ln2_b,
    const float* __restrict__ cls_w, const float* __restrict__ cls_b,
    float* __restrict__ qkv0, float* __restrict__ qkv1,
    unsigned* __restrict__ cnt, unsigned* __restrict__ pcnt,
    float* __restrict__ partial, float* __restrict__ out)
{
    // K planes interleaved [h][(r&3)*256 + (r>>2)]: staging writes conflict-
    // free (lanes consecutive 8B), frag reads 4-way (1.58x, acceptable).
    __shared__ uint2 KbP[2][1024];               // 16 KB bf16(beta*z) hi
    __shared__ uint2 KbL[2][1024];               // 16 KB residual lo
    __shared__ unsigned short VtH[8][1032];      // 16.5 KB bf16(z) transposed
    __shared__ float Olds[4][32][9];             // 4.6 KB per-wave PV partials
    __shared__ int isLast;

    const int bid = blockIdx.x;
    const int b = bid & 31;
    const int wgx = bid >> 5;
    const int tid = threadIdx.x;
    const float beta = 0.71423162f;   // sqrt(log2(e)/sqrt(8))

    const int w = tid >> 6;
    const int lane = tid & 63;
    const int ln = lane & 31;
    const int h = lane >> 5;
    const int qbase = wgx * 64 + (w >> 1) * 32;
    const int khalf = w & 1;
    const long grow = (long)b * SEQ + wgx * 64 + (tid & 63);

    // ---- embed + publish layer-0 qkv (own 64 rows; x stays in registers) ----
    float xv[8];
    if (tid < 64) {
        embed_row(tokens, emb, grow, wgx * 64 + tid, xv);
        float z[8]; qhead(xv, z);
        f32x4 z0 = {z[0], z[1], z[2], z[3]}, z1 = {z[4], z[5], z[6], z[7]};
        llc_store_row(qkv0 + grow * 8, z0, z1);
    }
    asm volatile("s_waitcnt vmcnt(0)" ::: "memory");
    if (tid == 0)
        __hip_atomic_fetch_add(&cnt[FL(0, b)], 1u,
                               __ATOMIC_RELAXED, __HIP_MEMORY_SCOPE_AGENT);

    for (int l = 0; l < 6; ++l) {
        float* qr = (l & 1) ? qkv1 : qkv0;
        float* qw = (l & 1) ? qkv0 : qkv1;

        if (tid == 0) {
            while (__hip_atomic_load(&cnt[FL(l, b)],
                                     __ATOMIC_RELAXED, __HIP_MEMORY_SCOPE_AGENT) < 16u)
                __builtin_amdgcn_s_sleep(4);
        }
        __syncthreads();

        // ---- single-pass stage: rows 4t..4t+3, one 128B LLC read ----
        {
            f32x4 d[8];
            llc_load_row4(qr + ((long)b * SEQ + tid * 4) * 8, d);
#pragma unroll
            for (int i = 0; i < 4; ++i) {
                unsigned ph[4], pl[4];
#pragma unroll
                for (int dd = 0; dd < 4; ++dd) {
                    float b0 = d[2 * i + (dd >> 1)][(2 * dd) & 3] * beta;
                    float b1 = d[2 * i + (dd >> 1)][(2 * dd + 1) & 3] * beta;
                    ph[dd] = cvt_pk_bf16(b0, b1);
                    pl[dd] = cvt_pk_bf16(b0 - bfu_lo(ph[dd]), b1 - bfu_hi(ph[dd]));
                }
                const int idx = (i << 8) | tid;   // interleaved row index
                KbP[0][idx] = make_uint2(ph[0], ph[1]);
                KbP[1][idx] = make_uint2(ph[2], ph[3]);
                KbL[0][idx] = make_uint2(pl[0], pl[1]);
                KbL[1][idx] = make_uint2(pl[2], pl[3]);
            }
#pragma unroll
            for (int c = 0; c < 8; ++c) {
                float v0 = d[0 + (c >> 2)][c & 3];
                float v1 = d[2 + (c >> 2)][c & 3];
                float v2 = d[4 + (c >> 2)][c & 3];
                float v3 = d[6 + (c >> 2)][c & 3];
                unsigned* dst = (unsigned*)&VtH[c][tid * 4];
                dst[0] = cvt_pk_bf16(v0, v1);
                dst[1] = cvt_pk_bf16(v2, v3);
            }
        }
        __syncthreads();

        // ---- MFMA attention: swapped QK^T (hi/lo scores), PV hi-only ----
        FragU qfB, qfB2;
        {
            const int qi = ((ln & 3) << 8) | ((qbase >> 2) + (ln >> 2));
            uint2 qh = KbP[h][qi], ql = KbL[h][qi];
            qfB.u[0] = qh.x; qfB.u[1] = qh.y; qfB.u[2] = qh.x; qfB.u[3] = qh.y;
            qfB2.u[0] = ql.x; qfB2.u[1] = ql.y; qfB2.u[2] = 0; qfB2.u[3] = 0;
        }
        f32x16 zc;
#pragma unroll
        for (int i = 0; i < 16; ++i) zc[i] = 0.f;
        f32x16 accA = zc, accB = zc;   // dual chains: halve MFMA dep latency
        const int lnk = ((ln & 3) << 8) | (ln >> 2);

        for (int t = 0; t < 16; ++t) {
            const int kbase = (khalf * 16 + t) * 32;
            const int ki = lnk + (kbase >> 2);
            uint2 kh = KbP[h][ki], kl = KbL[h][ki];
            FragU kfA, kfA2;
            kfA.u[0] = kh.x; kfA.u[1] = kh.y; kfA.u[2] = kl.x; kfA.u[3] = kl.y;
            kfA2.u[0] = kh.x; kfA2.u[1] = kh.y; kfA2.u[2] = 0; kfA2.u[3] = 0;
            // s = kh*qh + kl*qh + kh*ql   (kl*ql ~2^-18, dropped)
            f32x16 s = __builtin_amdgcn_mfma_f32_32x32x16_bf16(kfA2.s, qfB2.s, zc, 0, 0, 0);
            s = __builtin_amdgcn_mfma_f32_32x32x16_bf16(kfA.s, qfB.s, s, 0, 0, 0);
            float p[16];
#pragma unroll
            for (int g = 0; g < 16; ++g) p[g] = exp2f(s[g]);

            FragU a1, a2;
#pragma unroll
            for (int vi = 0; vi < 4; ++vi) {
                a1.u[vi] = cvt_pk_bf16(p[2 * vi], p[2 * vi + 1]);
                a2.u[vi] = cvt_pk_bf16(p[8 + 2 * vi], p[8 + 2 * vi + 1]);
            }
            FragU v1h, v2h;
            if (ln < 8) {
                const unsigned* r0 = (const unsigned*)&VtH[ln][kbase + 4 * h];
                const unsigned* r1 = (const unsigned*)&VtH[ln][kbase + 8 + 4 * h];
                const unsigned* r2 = (const unsigned*)&VtH[ln][kbase + 16 + 4 * h];
                const unsigned* r3 = (const unsigned*)&VtH[ln][kbase + 24 + 4 * h];
                v1h.u[0] = r0[0]; v1h.u[1] = r0[1]; v1h.u[2] = r1[0]; v1h.u[3] = r1[1];
                v2h.u[0] = r2[0]; v2h.u[1] = r2[1]; v2h.u[2] = r3[0]; v2h.u[3] = r3[1];
            } else if (ln == 8) {
#pragma unroll
                for (int i = 0; i < 4; ++i) { v1h.u[i] = 0x3F803F80u; v2h.u[i] = 0x3F803F80u; }
            } else {
#pragma unroll
                for (int i = 0; i < 4; ++i) { v1h.u[i] = 0; v2h.u[i] = 0; }
            }
            accA = __builtin_amdgcn_mfma_f32_32x32x16_bf16(a1.s, v1h.s, accA, 0, 0, 0);
            accB = __builtin_amdgcn_mfma_f32_32x32x16_bf16(a2.s, v2h.s, accB, 0, 0, 0);
        }

        if (ln <= 8) {
#pragma unroll
            for (int g = 0; g < 16; ++g)
                Olds[w][(g & 3) + 8 * (g >> 2) + 4 * h][ln] = accA[g] + accB[g];
        }
        __syncthreads();

        // ---- epilogue: wave 0, one thread per row; x in registers ----
        if (tid < 64) {
            const int rr = tid & 31;
            const int w0 = (tid >> 5) * 2;
            float o[9];
#pragma unroll
            for (int c = 0; c < 9; ++c) o[c] = Olds[w0][rr][c] + Olds[w0 + 1][rr][c];
            float inv = 1.0f / o[8];
            float outv[8];
#pragma unroll
            for (int c = 0; c < 8; ++c) outv[c] = o[c] * inv;

            const float* W  = attn_w + l * 64; const float* Wb  = attn_b + l * 8;
            const float* g1 = ln1_g + l * 8;   const float* b1v = ln1_b + l * 8;
            const float* W1 = ffn_w1 + l * 64; const float* c1  = ffn_b1 + l * 8;
            const float* W2 = ffn_w2 + l * 64; const float* c2  = ffn_b2 + l * 8;
            const float* g2 = ln2_g + l * 8;   const float* b2v = ln2_b + l * 8;

            float y[8]; float m = 0.f;
#pragma unroll
            for (int j = 0; j < 8; ++j) {
                float vv = Wb[j];
#pragma unroll
                for (int i = 0; i < 8; ++i) vv += outv[i] * W[i * 8 + j];
                y[j] = xv[j] + vv;
                m += y[j];
            }
            m *= 0.125f;
            float var = 0.f;
#pragma unroll
            for (int j = 0; j < 8; ++j) { float dd = y[j] - m; var += dd * dd; }
            var *= 0.125f;
            float rsg = rsqrtf(var + LNEPS);
            float xn[8];
#pragma unroll
            for (int j = 0; j < 8; ++j) xn[j] = g1[j] * (y[j] - m) * rsg + b1v[j];

            float hh[8];
#pragma unroll
            for (int j = 0; j < 8; ++j) {
                float vv = c1[j];
#pragma unroll
                for (int i = 0; i < 8; ++i) vv += xn[i] * W1[i * 8 + j];
                hh[j] = vv;
            }
            float qff[8]; qhead(hh, qff);
            float m2 = 0.f;
#pragma unroll
            for (int j = 0; j < 8; ++j) {
                float vv = c2[j];
#pragma unroll
                for (int i = 0; i < 8; ++i) vv += qff[i] * W2[i * 8 + j];
                y[j] = xn[j] + vv;
                m2 += y[j];
            }
            m2 *= 0.125f;
            float var2 = 0.f;
#pragma unroll
            for (int j = 0; j < 8; ++j) { float dd = y[j] - m2; var2 += dd * dd; }
            var2 *= 0.125f;
            float rs2 = rsqrtf(var2 + LNEPS);
#pragma unroll
            for (int j = 0; j < 8; ++j) xv[j] = g2[j] * (y[j] - m2) * rs2 + b2v[j];

            if (l < 5) {
                float z[8]; qhead(xv, z);
                f32x4 z0 = {z[0], z[1], z[2], z[3]}, z1 = {z[4], z[5], z[6], z[7]};
                llc_store_row(qw + grow * 8, z0, z1);
            }
        }
        if (l < 5) {
            asm volatile("s_waitcnt vmcnt(0)" ::: "memory");
            if (tid == 0)
                __hip_atomic_fetch_add(&cnt[FL(l + 1, b)], 1u,
                                       __ATOMIC_RELAXED, __HIP_MEMORY_SCOPE_AGENT);
        }
    }

    // ---- pool + classifier: last-WG-per-batch, fence-free (R8-proven) ----
    if (tid < 64) {
        float a[8];
#pragma unroll
        for (int j = 0; j < 8; ++j) {
            a[j] = xv[j];
#pragma unroll
            for (int off = 1; off <= 32; off <<= 1) a[j] += __shfl_xor(a[j], off);
        }
        if (tid < 8) sys_store(&partial[(b * 16 + wgx) * 8 + tid], a[tid]);
    }
    asm volatile("s_waitcnt vmcnt(0)" ::: "memory");
    __syncthreads();
    if (tid == 0) {
        unsigned r = __hip_atomic_fetch_add(&pcnt[b * 16], 1u,
                                            __ATOMIC_RELAXED, __HIP_MEMORY_SCOPE_AGENT);
        isLast = (r == 15u);
    }
    __syncthreads();
    if (isLast && tid < 64) {
        int g = tid >> 3, j = tid & 7;
        float s = sys_load(&partial[(b * 16 + g) * 8 + j])
                + sys_load(&partial[(b * 16 + g + 8) * 8 + j]);
        s += __shfl_xor(s, 8); s += __shfl_xor(s, 16); s += __shfl_xor(s, 32);
        float poolj = s * (1.0f / 1024.0f);
        int c = tid < 10 ? tid : 9;
        float o = cls_b[c];
#pragma unroll
        for (int j2 = 0; j2 < 8; ++j2)
            o += __shfl(poolj, j2) * cls_w[j2 * 10 + c];
        if (tid < 10) out[b * 10 + tid] = o;
    }
}

extern "C" void kernel_launch(void* const* d_in, const int* in_sizes, int n_in,
                              void* d_out, int out_size, void* d_ws, size_t ws_size,
                              hipStream_t stream) {
    const int*   tokens = (const int*)d_in[0];
    const float* emb    = (const float*)d_in[1];
    const float* ln1_g  = (const float*)d_in[2];
    const float* ln1_b  = (const float*)d_in[3];
    const float* ln2_g  = (const float*)d_in[4];
    const float* ln2_b  = (const float*)d_in[5];
    const float* attn_w = (const float*)d_in[6];
    const float* attn_b = (const float*)d_in[7];
    const float* ffn_w1 = (const float*)d_in[8];
    const float* ffn_b1 = (const float*)d_in[9];
    const float* ffn_w2 = (const float*)d_in[10];
    const float* ffn_b2 = (const float*)d_in[11];
    const float* cls_w  = (const float*)d_in[12];
    const float* cls_b  = (const float*)d_in[13];

    // ws (f32 words): cnt 3072 | pcnt 512 | partial 4096 | qkv0 1MB | qkv1 1MB
    unsigned* cnt     = (unsigned*)d_ws;
    unsigned* pcnt    = cnt + 3072;
    float*    partial = (float*)d_ws + 3584;
    float*    qkv0    = (float*)d_ws + 3584 + 4096;
    float*    qkv1    = qkv0 + (long)NROWS * 8;
    float*    outp    = (float*)d_out;

    zero_flags<<<1, 1024, 0, stream>>>(cnt);   // zeroes cnt + pcnt
    qt_fused<<<512, 256, 0, stream>>>(
        tokens, emb, attn_w, attn_b, ln1_g, ln1_b,
        ffn_w1, ffn_b1, ffn_w2, ffn_b2, ln2_g, ln2_b,
        cls_w, cls_b, qkv0, qkv1, cnt, pcnt, partial, outp);
}

// Round 10
// 104.462 us; speedup vs baseline: 4.6838x; 1.0543x over previous
//
#include <hip/hip_runtime.h>
#include <math.h>

#define EMB 8
#define SEQ 1024
#define NBATCH 32
#define NROWS (NBATCH * SEQ)
#define LNEPS 1e-5f
#define FL(l, b) (((l) * 32 + (b)) * 16)

typedef __attribute__((ext_vector_type(4))) float f32x4;
typedef __attribute__((ext_vector_type(8))) _Float16 f16x8;
typedef __attribute__((ext_vector_type(16))) float f32x16;

union FragU { unsigned u[4]; f16x8 s; };

__device__ __forceinline__ unsigned pkrtz(float a, float b) {
    unsigned r;
    asm("v_cvt_pkrtz_f16_f32 %0, %1, %2" : "=v"(r) : "v"(a), "v"(b));
    return r;
}

// LLC-coherent (sc0 sc1) accessors: bypass L1/L2, land at the cross-XCD
// coherence point. No cache-wide maintenance anywhere (R7's poison).
__device__ __forceinline__ void llc_load_row4(const float* p, f32x4 d[8]) {
    asm volatile(
        "global_load_dwordx4 %0, %[a], off sc0 sc1\n\t"
        "global_load_dwordx4 %1, %[a], off offset:16 sc0 sc1\n\t"
        "global_load_dwordx4 %2, %[a], off offset:32 sc0 sc1\n\t"
        "global_load_dwordx4 %3, %[a], off offset:48 sc0 sc1\n\t"
        "global_load_dwordx4 %4, %[a], off offset:64 sc0 sc1\n\t"
        "global_load_dwordx4 %5, %[a], off offset:80 sc0 sc1\n\t"
        "global_load_dwordx4 %6, %[a], off offset:96 sc0 sc1\n\t"
        "global_load_dwordx4 %7, %[a], off offset:112 sc0 sc1\n\t"
        "s_waitcnt vmcnt(0)"
        : "=&v"(d[0]), "=&v"(d[1]), "=&v"(d[2]), "=&v"(d[3]),
          "=&v"(d[4]), "=&v"(d[5]), "=&v"(d[6]), "=&v"(d[7])
        : [a] "v"(p) : "memory");
}
__device__ __forceinline__ void llc_store_row(float* p, f32x4 a, f32x4 b) {
    asm volatile(
        "global_store_dwordx4 %[a], %[x], off sc0 sc1\n\t"
        "global_store_dwordx4 %[a], %[y], off offset:16 sc0 sc1"
        :: [a] "v"(p), [x] "v"(a), [y] "v"(b) : "memory");
}
__device__ __forceinline__ void sys_store(float* p, float v) {
    asm volatile("global_store_dword %0, %1, off sc0 sc1" :: "v"(p), "v"(v) : "memory");
}
__device__ __forceinline__ float sys_load(const float* p) {
    float r;
    asm volatile("global_load_dword %0, %1, off sc0 sc1\n\ts_waitcnt vmcnt(0)"
                 : "=v"(r) : "v"(p) : "memory");
    return r;
}

// Closed-form quantum head: RX layer + Clifford (CNOT chain + H) conjugates
// each Z_i into a product of cos(x_j) (even/odd prefix products).
__device__ __forceinline__ void qhead(const float xv[8], float z[8]) {
    float c[8];
#pragma unroll
    for (int j = 0; j < 8; ++j) c[j] = __cosf(xv[j]);
    float e0 = c[0];
    float o1 = c[1];
    float e2 = e0 * c[2];
    float o3 = o1 * c[3];
    float e4 = e2 * c[4];
    float o5 = o3 * c[5];
    float e6 = e4 * c[6];
    z[0] = e0; z[1] = o1; z[2] = e2; z[3] = o3;
    z[4] = e4; z[5] = o5; z[6] = e6;
    z[7] = e6 * o5 * c[7];
}

__device__ __forceinline__ void embed_row(const int* __restrict__ tokens,
                                          const float* __restrict__ emb,
                                          long grow, int srow, float xv[8]) {
    int tok = tokens[grow];
    const float* e = emb + (long)tok * EMB;
    float p = (float)srow;
    xv[0] = e[0] + sinf(p);
    xv[1] = e[1] + cosf(p);
    xv[2] = e[2] + sinf(p * 0.1f);
    xv[3] = e[3] + cosf(p * 0.1f);
    xv[4] = e[4] + sinf(p * 0.01f);
    xv[5] = e[5] + cosf(p * 0.01f);
    xv[6] = e[6] + sinf(p * 0.001f);
    xv[7] = e[7] + cosf(p * 0.001f);
}

// Flags must be zero at kernel start each call (harness poisons ws once).
__global__ __launch_bounds__(1024) void zero_flags(unsigned* __restrict__ f) {
    for (int i = threadIdx.x; i < 3584; i += 1024) f[i] = 0u;
}

// Whole model, one persistent kernel. 512 WGs x 512 threads (8 waves):
// wave w -> q-tile (w>>2), key-quarter (w&3), 8 tiles each. 42 KB LDS +
// launch_bounds(512,4) => 2 WG/CU => all 512 co-resident (R9-proven shape)
// and 16 waves/CU = 4 waves/SIMD (2x R9's latency hiding).
// All operands fp16 (2^-10 rtz << bf16 2^-8): QK = ONE MFMA, PV = 2.
__global__ __launch_bounds__(512, 4) void qt_fused(
    const int* __restrict__ tokens, const float* __restrict__ emb,
    const float* __restrict__ attn_w, const float* __restrict__ attn_b,
    const float* __restrict__ ln1_g, const float* __restrict__ ln1_b,
    const float* __restrict__ ffn_w1, const float* __restrict__ ffn_b1,
    const float* __restrict__ ffn_w2, const float* __restrict__ ffn_b2,
    const float* __restrict__ ln2_g, const float* __restrict__ ln2_b,
    const float* __restrict__ cls_w, const float* __restrict__ cls_b,
    float* __restrict__ qkv0, float* __restrict__ qkv1,
    unsigned* __restrict__ cnt, unsigned* __restrict__ pcnt,
    float* __restrict__ partial, float* __restrict__ out)
{
    // K planes [h][col-rotated]: row r at col ((r>>2)+8*(r&3))&255, block r&3.
    // Staging writes consecutive; frag reads <=2-way bank aliasing (free).
    __shared__ uint2 KbP[2][1024];               // 16 KB fp16(beta*z)
    __shared__ unsigned short VtH[8][1032];      // 16.5 KB fp16(z) transposed
    __shared__ float Olds[8][32][9];             // 9.2 KB per-wave PV partials
    __shared__ int isLast;

    const int bid = blockIdx.x;
    const int b = bid & 31;          // batch: its 16 WGs share an XCD
    const int wgx = bid >> 5;        // 64-row chunk
    const int tid = threadIdx.x;
    const float beta = 0.71423162f;  // sqrt(log2(e)/sqrt(8))

    const int w = tid >> 6;
    const int lane = tid & 63;
    const int ln = lane & 31;
    const int h = lane >> 5;
    const int qbase = wgx * 64 + (w >> 2) * 32;
    const int qu = w & 3;            // key quarter
    const long grow = (long)b * SEQ + wgx * 64 + (tid & 63);

    // ---- embed + publish layer-0 qkv (own 64 rows; x stays in registers) ----
    float xv[8];
    if (tid < 64) {
        embed_row(tokens, emb, grow, wgx * 64 + tid, xv);
        float z[8]; qhead(xv, z);
        f32x4 z0 = {z[0], z[1], z[2], z[3]}, z1 = {z[4], z[5], z[6], z[7]};
        llc_store_row(qkv0 + grow * 8, z0, z1);
    }
    asm volatile("s_waitcnt vmcnt(0)" ::: "memory");
    if (tid == 0)
        __hip_atomic_fetch_add(&cnt[FL(0, b)], 1u,
                               __ATOMIC_RELAXED, __HIP_MEMORY_SCOPE_AGENT);

    for (int l = 0; l < 6; ++l) {
        float* qr = (l & 1) ? qkv1 : qkv0;
        float* qw = (l & 1) ? qkv0 : qkv1;

        if (tid == 0) {
            while (__hip_atomic_load(&cnt[FL(l, b)],
                                     __ATOMIC_RELAXED, __HIP_MEMORY_SCOPE_AGENT) < 16u)
                __builtin_amdgcn_s_sleep(4);
        }
        __syncthreads();

        // ---- stage (first 256 threads): rows 4t..4t+3, one 128B LLC read ----
        if (tid < 256) {
            f32x4 d[8];
            llc_load_row4(qr + ((long)b * SEQ + tid * 4) * 8, d);
#pragma unroll
            for (int i = 0; i < 4; ++i) {
                float z0 = d[2 * i][0] * beta, z1 = d[2 * i][1] * beta;
                float z2 = d[2 * i][2] * beta, z3 = d[2 * i][3] * beta;
                float z4 = d[2 * i + 1][0] * beta, z5 = d[2 * i + 1][1] * beta;
                float z6 = d[2 * i + 1][2] * beta, z7 = d[2 * i + 1][3] * beta;
                const int col = (tid + 8 * i) & 255;        // rotation swizzle
                KbP[0][(i << 8) | col] = make_uint2(pkrtz(z0, z1), pkrtz(z2, z3));
                KbP[1][(i << 8) | col] = make_uint2(pkrtz(z4, z5), pkrtz(z6, z7));
            }
#pragma unroll
            for (int c = 0; c < 8; ++c) {
                float v0 = d[0 + (c >> 2)][c & 3];
                float v1 = d[2 + (c >> 2)][c & 3];
                float v2 = d[4 + (c >> 2)][c & 3];
                float v3 = d[6 + (c >> 2)][c & 3];
                unsigned* dst = (unsigned*)&VtH[c][tid * 4];
                dst[0] = pkrtz(v0, v1);
                dst[1] = pkrtz(v2, v3);
            }
        }
        __syncthreads();

        // ---- MFMA attention: swapped QK^T, all fp16 ----
        FragU qfB;
        {
            const int qcol = ((qbase >> 2) + (ln >> 2) + 8 * (ln & 3)) & 255;
            uint2 qh = KbP[h][((ln & 3) << 8) | qcol];
            qfB.u[0] = qh.x; qfB.u[1] = qh.y; qfB.u[2] = qh.x; qfB.u[3] = qh.y;
        }
        f32x16 zc;
#pragma unroll
        for (int i = 0; i < 16; ++i) zc[i] = 0.f;
        f32x16 accA = zc, accB = zc;   // dual PV chains

#pragma unroll 2
        for (int t = 0; t < 8; ++t) {
            const int kbase = ((qu << 3) | t) << 5;
            FragU kfA;
            {
                const int kcol = ((kbase >> 2) + (ln >> 2) + 8 * (ln & 3)) & 255;
                uint2 kh = KbP[h][((ln & 3) << 8) | kcol];
                kfA.u[0] = kh.x; kfA.u[1] = kh.y; kfA.u[2] = 0; kfA.u[3] = 0;
            }
            f32x16 s = __builtin_amdgcn_mfma_f32_32x32x16_f16(kfA.s, qfB.s, zc, 0, 0, 0);
            float p[16];
#pragma unroll
            for (int g = 0; g < 16; ++g) p[g] = exp2f(s[g]);

            FragU a1, a2;
#pragma unroll
            for (int vi = 0; vi < 4; ++vi) {
                a1.u[vi] = pkrtz(p[2 * vi], p[2 * vi + 1]);
                a2.u[vi] = pkrtz(p[8 + 2 * vi], p[8 + 2 * vi + 1]);
            }
            FragU v1h, v2h;
            if (ln < 8) {
                const unsigned* r0 = (const unsigned*)&VtH[ln][kbase + 4 * h];
                const unsigned* r1 = (const unsigned*)&VtH[ln][kbase + 8 + 4 * h];
                const unsigned* r2 = (const unsigned*)&VtH[ln][kbase + 16 + 4 * h];
                const unsigned* r3 = (const unsigned*)&VtH[ln][kbase + 24 + 4 * h];
                v1h.u[0] = r0[0]; v1h.u[1] = r0[1]; v1h.u[2] = r1[0]; v1h.u[3] = r1[1];
                v2h.u[0] = r2[0]; v2h.u[1] = r2[1]; v2h.u[2] = r3[0]; v2h.u[3] = r3[1];
            } else if (ln == 8) {
#pragma unroll
                for (int i = 0; i < 4; ++i) { v1h.u[i] = 0x3C003C00u; v2h.u[i] = 0x3C003C00u; }
            } else {
#pragma unroll
                for (int i = 0; i < 4; ++i) { v1h.u[i] = 0; v2h.u[i] = 0; }
            }
            accA = __builtin_amdgcn_mfma_f32_32x32x16_f16(a1.s, v1h.s, accA, 0, 0, 0);
            accB = __builtin_amdgcn_mfma_f32_32x32x16_f16(a2.s, v2h.s, accB, 0, 0, 0);
        }

        if (ln <= 8) {
#pragma unroll
            for (int g = 0; g < 16; ++g)
                Olds[w][(g & 3) + 8 * (g >> 2) + 4 * h][ln] = accA[g] + accB[g];
        }
        __syncthreads();

        // ---- epilogue: wave 0, one thread per row; x in registers ----
        if (tid < 64) {
            const int rr = tid & 31;
            const int w0 = (tid >> 5) * 4;
            float o[9];
#pragma unroll
            for (int c = 0; c < 9; ++c)
                o[c] = (Olds[w0][rr][c] + Olds[w0 + 1][rr][c])
                     + (Olds[w0 + 2][rr][c] + Olds[w0 + 3][rr][c]);
            float inv = 1.0f / o[8];
            float outv[8];
#pragma unroll
            for (int c = 0; c < 8; ++c) outv[c] = o[c] * inv;

            const float* W  = attn_w + l * 64; const float* Wb  = attn_b + l * 8;
            const float* g1 = ln1_g + l * 8;   const float* b1v = ln1_b + l * 8;
            const float* W1 = ffn_w1 + l * 64; const float* c1  = ffn_b1 + l * 8;
            const float* W2 = ffn_w2 + l * 64; const float* c2  = ffn_b2 + l * 8;
            const float* g2 = ln2_g + l * 8;   const float* b2v = ln2_b + l * 8;

            float y[8]; float m = 0.f;
#pragma unroll
            for (int j = 0; j < 8; ++j) {
                float vv = Wb[j];
#pragma unroll
                for (int i = 0; i < 8; ++i) vv += outv[i] * W[i * 8 + j];
                y[j] = xv[j] + vv;
                m += y[j];
            }
            m *= 0.125f;
            float var = 0.f;
#pragma unroll
            for (int j = 0; j < 8; ++j) { float dd = y[j] - m; var += dd * dd; }
            var *= 0.125f;
            float rsg = rsqrtf(var + LNEPS);
            float xn[8];
#pragma unroll
            for (int j = 0; j < 8; ++j) xn[j] = g1[j] * (y[j] - m) * rsg + b1v[j];

            float hh[8];
#pragma unroll
            for (int j = 0; j < 8; ++j) {
                float vv = c1[j];
#pragma unroll
                for (int i = 0; i < 8; ++i) vv += xn[i] * W1[i * 8 + j];
                hh[j] = vv;
            }
            float qff[8]; qhead(hh, qff);
            float m2 = 0.f;
#pragma unroll
            for (int j = 0; j < 8; ++j) {
                float vv = c2[j];
#pragma unroll
                for (int i = 0; i < 8; ++i) vv += qff[i] * W2[i * 8 + j];
                y[j] = xn[j] + vv;
                m2 += y[j];
            }
            m2 *= 0.125f;
            float var2 = 0.f;
#pragma unroll
            for (int j = 0; j < 8; ++j) { float dd = y[j] - m2; var2 += dd * dd; }
            var2 *= 0.125f;
            float rs2 = rsqrtf(var2 + LNEPS);
#pragma unroll
            for (int j = 0; j < 8; ++j) xv[j] = g2[j] * (y[j] - m2) * rs2 + b2v[j];

            if (l < 5) {
                float z[8]; qhead(xv, z);
                f32x4 z0 = {z[0], z[1], z[2], z[3]}, z1 = {z[4], z[5], z[6], z[7]};
                llc_store_row(qw + grow * 8, z0, z1);
            }
        }
        if (l < 5) {
            asm volatile("s_waitcnt vmcnt(0)" ::: "memory");
            if (tid == 0)
                __hip_atomic_fetch_add(&cnt[FL(l + 1, b)], 1u,
                                       __ATOMIC_RELAXED, __HIP_MEMORY_SCOPE_AGENT);
        }
    }

    // ---- pool + classifier: last-WG-per-batch, fence-free (R8/R9-proven) ----
    if (tid < 64) {
        float a[8];
#pragma unroll
        for (int j = 0; j < 8; ++j) {
            a[j] = xv[j];
#pragma unroll
            for (int off = 1; off <= 32; off <<= 1) a[j] += __shfl_xor(a[j], off);
        }
        if (tid < 8) sys_store(&partial[(b * 16 + wgx) * 8 + tid], a[tid]);
    }
    asm volatile("s_waitcnt vmcnt(0)" ::: "memory");
    __syncthreads();
    if (tid == 0) {
        unsigned r = __hip_atomic_fetch_add(&pcnt[b * 16], 1u,
                                            __ATOMIC_RELAXED, __HIP_MEMORY_SCOPE_AGENT);
        isLast = (r == 15u);
    }
    __syncthreads();
    if (isLast && tid < 64) {
        int g = tid >> 3, j = tid & 7;
        float s = sys_load(&partial[(b * 16 + g) * 8 + j])
                + sys_load(&partial[(b * 16 + g + 8) * 8 + j]);
        s += __shfl_xor(s, 8); s += __shfl_xor(s, 16); s += __shfl_xor(s, 32);
        float poolj = s * (1.0f / 1024.0f);
        int c = tid < 10 ? tid : 9;
        float o = cls_b[c];
#pragma unroll
        for (int j2 = 0; j2 < 8; ++j2)
            o += __shfl(poolj, j2) * cls_w[j2 * 10 + c];
        if (tid < 10) out[b * 10 + tid] = o;
    }
}

extern "C" void kernel_launch(void* const* d_in, const int* in_sizes, int n_in,
                              void* d_out, int out_size, void* d_ws, size_t ws_size,
                              hipStream_t stream) {
    const int*   tokens = (const int*)d_in[0];
    const float* emb    = (const float*)d_in[1];
    const float* ln1_g  = (const float*)d_in[2];
    const float* ln1_b  = (const float*)d_in[3];
    const float* ln2_g  = (const float*)d_in[4];
    const float* ln2_b  = (const float*)d_in[5];
    const float* attn_w = (const float*)d_in[6];
    const float* attn_b = (const float*)d_in[7];
    const float* ffn_w1 = (const float*)d_in[8];
    const float* ffn_b1 = (const float*)d_in[9];
    const float* ffn_w2 = (const float*)d_in[10];
    const float* ffn_b2 = (const float*)d_in[11];
    const float* cls_w  = (const float*)d_in[12];
    const float* cls_b  = (const float*)d_in[13];

    // ws (f32 words): cnt 3072 | pcnt 512 | partial 4096 | qkv0 1MB | qkv1 1MB
    unsigned* cnt     = (unsigned*)d_ws;
    unsigned* pcnt    = cnt + 3072;
    float*    partial = (float*)d_ws + 3584;
    float*    qkv0    = (float*)d_ws + 3584 + 4096;
    float*    qkv1    = qkv0 + (long)NROWS * 8;
    float*    outp    = (float*)d_out;

    zero_flags<<<1, 1024, 0, stream>>>(cnt);   // zeroes cnt + pcnt
    qt_fused<<<512, 512, 0, stream>>>(
        tokens, emb, attn_w, attn_b, ln1_g, ln1_b,
        ffn_w1, ffn_b1, ffn_w2, ffn_b2, ln2_g, ln2_b,
        cls_w, cls_b, qkv0, qkv1, cnt, pcnt, partial, outp);
}

// Round 11
// 101.122 us; speedup vs baseline: 4.8385x; 1.0330x over previous
//
#include <hip/hip_runtime.h>
#include <math.h>

#define EMB 8
#define SEQ 1024
#define NBATCH 32
#define NROWS (NBATCH * SEQ)
#define LNEPS 1e-5f
#define F(l, b, c) (((l) * 32 + (b)) * 16 + (c))

typedef __attribute__((ext_vector_type(4))) float f32x4;
typedef __attribute__((ext_vector_type(8))) _Float16 f16x8;
typedef __attribute__((ext_vector_type(16))) float f32x16;

union FragU { unsigned u[4]; f16x8 s; };

__device__ __forceinline__ unsigned pkrtz(float a, float b) {
    unsigned r;
    asm("v_cvt_pkrtz_f16_f32 %0, %1, %2" : "=v"(r) : "v"(a), "v"(b));
    return r;
}

// LLC-coherent (sc0 sc1) accessors: bypass L1/L2, land at the cross-XCD
// coherence point. No cache-wide maintenance anywhere.
__device__ __forceinline__ void llc_load_row2(const float* p, f32x4 d[4]) {
    asm volatile(
        "global_load_dwordx4 %0, %[a], off sc0 sc1\n\t"
        "global_load_dwordx4 %1, %[a], off offset:16 sc0 sc1\n\t"
        "global_load_dwordx4 %2, %[a], off offset:32 sc0 sc1\n\t"
        "global_load_dwordx4 %3, %[a], off offset:48 sc0 sc1\n\t"
        "s_waitcnt vmcnt(0)"
        : "=&v"(d[0]), "=&v"(d[1]), "=&v"(d[2]), "=&v"(d[3])
        : [a] "v"(p) : "memory");
}
__device__ __forceinline__ void llc_store_row(float* p, f32x4 a, f32x4 b) {
    asm volatile(
        "global_store_dwordx4 %[a], %[x], off sc0 sc1\n\t"
        "global_store_dwordx4 %[a], %[y], off offset:16 sc0 sc1"
        :: [a] "v"(p), [x] "v"(a), [y] "v"(b) : "memory");
}
__device__ __forceinline__ void sys_store(float* p, float v) {
    asm volatile("global_store_dword %0, %1, off sc0 sc1" :: "v"(p), "v"(v) : "memory");
}
__device__ __forceinline__ float sys_load(const float* p) {
    float r;
    asm volatile("global_load_dword %0, %1, off sc0 sc1\n\ts_waitcnt vmcnt(0)"
                 : "=v"(r) : "v"(p) : "memory");
    return r;
}
__device__ __forceinline__ unsigned sys_load_u32(const unsigned* p) {
    unsigned r;
    asm volatile("global_load_dword %0, %1, off sc0 sc1\n\ts_waitcnt vmcnt(0)"
                 : "=v"(r) : "v"(p) : "memory");
    return r;
}
__device__ __forceinline__ void sys_store_u32(unsigned* p, unsigned v) {
    asm volatile("global_store_dword %0, %1, off sc0 sc1" :: "v"(p), "v"(v) : "memory");
}

// Closed-form quantum head: RX layer + Clifford (CNOT chain + H) conjugates
// each Z_i into a product of cos(x_j) (even/odd prefix products).
__device__ __forceinline__ void qhead(const float xv[8], float z[8]) {
    float c[8];
#pragma unroll
    for (int j = 0; j < 8; ++j) c[j] = __cosf(xv[j]);
    float e0 = c[0];
    float o1 = c[1];
    float e2 = e0 * c[2];
    float o3 = o1 * c[3];
    float e4 = e2 * c[4];
    float o5 = o3 * c[5];
    float e6 = e4 * c[6];
    z[0] = e0; z[1] = o1; z[2] = e2; z[3] = o3;
    z[4] = e4; z[5] = o5; z[6] = e6;
    z[7] = e6 * o5 * c[7];
}

__device__ __forceinline__ void embed_row(const int* __restrict__ tokens,
                                          const float* __restrict__ emb,
                                          long grow, int srow, float xv[8]) {
    int tok = tokens[grow];
    const float* e = emb + (long)tok * EMB;
    float p = (float)srow;
    xv[0] = e[0] + sinf(p);
    xv[1] = e[1] + cosf(p);
    xv[2] = e[2] + sinf(p * 0.1f);
    xv[3] = e[3] + cosf(p * 0.1f);
    xv[4] = e[4] + sinf(p * 0.01f);
    xv[5] = e[5] + cosf(p * 0.01f);
    xv[6] = e[6] + sinf(p * 0.001f);
    xv[7] = e[7] + cosf(p * 0.001f);
}

// Flags must be zero at kernel start each call (harness poisons ws once).
__global__ __launch_bounds__(1024) void zero_flags(unsigned* __restrict__ f) {
    for (int i = threadIdx.x; i < 3584; i += 1024) f[i] = 0u;
}

// Whole model, one persistent kernel, 2-batch software pipeline.
// Grid 256 WGs x 512 thr: group = bid&15 owns batches {2g, 2g+1}; chunk =
// bid>>4 owns rows [chunk*64, chunk*64+64). Grid <= #CUs => all co-resident.
// Per layer, phases A,B: stage(poll per-producer flag + LLC load) -> barrier
// -> MFMA -> Olds -> barrier -> epilogue(wave ph) || next-phase stage.
// Publish: epilogue wave stores rows (sc0sc1), wave-level vmcnt(0), lane 0
// stores flag -- single-writer, no atomics. Phase B's compute hides phase A's
// publish latency and vice versa => steady-state zero sync wait.
__global__ __launch_bounds__(512, 2) void qt_fused(
    const int* __restrict__ tokens, const float* __restrict__ emb,
    const float* __restrict__ attn_w, const float* __restrict__ attn_b,
    const float* __restrict__ ln1_g, const float* __restrict__ ln1_b,
    const float* __restrict__ ffn_w1, const float* __restrict__ ffn_b1,
    const float* __restrict__ ffn_w2, const float* __restrict__ ffn_b2,
    const float* __restrict__ ln2_g, const float* __restrict__ ln2_b,
    const float* __restrict__ cls_w, const float* __restrict__ cls_b,
    float* __restrict__ qkv0, float* __restrict__ qkv1,
    unsigned* __restrict__ flags, unsigned* __restrict__ pcnt,
    float* __restrict__ partial, float* __restrict__ out)
{
    __shared__ __align__(16) uint2 KbP[2][1024];        // 16 KB fp16(beta*z), [h][row]
    __shared__ __align__(16) unsigned short VtH[8][1032]; // 16.5 KB fp16(z) transposed
    __shared__ float Olds[8][32][9];                    // 9.2 KB PV partials
    __shared__ float x_lds[2][64][8];                   // 4 KB residual stream (per phase)
    __shared__ int isL[2];

    const int bid = blockIdx.x;
    const int group = bid & 15;     // group's 16 WGs share an XCD (round-robin)
    const int chunk = bid >> 4;
    const int tid = threadIdx.x;
    const float beta = 0.71423162f; // sqrt(log2(e)/sqrt(8))

    const int w = tid >> 6;
    const int lane = tid & 63;
    const int ln = lane & 31;
    const int h = lane >> 5;
    const int qtile = w >> 2;       // 0..1
    const int qu = w & 3;           // key quarter
    const int r0 = tid * 2;         // this thread's 2 staging rows

    for (int l = 0; l < 6; ++l) {
        const float* qr = (l & 1) ? qkv1 : qkv0;
        float* qw = (l & 1) ? qkv0 : qkv1;
        for (int ph = 0; ph < 2; ++ph) {
            const int bb = group * 2 + ph;
            // ---------------- stage: rows r0, r0+1 ----------------
            {
                float v0[8], v1[8];
                if (l == 0) {
                    float e0[8], e1[8];
                    embed_row(tokens, emb, (long)bb * SEQ + r0, r0, e0);
                    embed_row(tokens, emb, (long)bb * SEQ + r0 + 1, r0 + 1, e1);
                    if ((r0 >> 6) == chunk) {
                        const int lr = r0 - chunk * 64;
#pragma unroll
                        for (int j = 0; j < 8; ++j) {
                            x_lds[ph][lr][j] = e0[j];
                            x_lds[ph][lr + 1][j] = e1[j];
                        }
                    }
                    qhead(e0, v0); qhead(e1, v1);
                } else {
                    // per-thread dataflow wait on this thread's producer only
                    const unsigned* fp = &flags[F(l, bb, r0 >> 6)];
                    while (sys_load_u32(fp) == 0u) __builtin_amdgcn_s_sleep(1);
                    f32x4 d[4];
                    llc_load_row2(qr + ((long)bb * SEQ + r0) * 8, d);
#pragma unroll
                    for (int j = 0; j < 4; ++j) {
                        v0[j] = d[0][j]; v0[4 + j] = d[1][j];
                        v1[j] = d[2][j]; v1[4 + j] = d[3][j];
                    }
                }
                uint4 k0, k1;
                k0.x = pkrtz(v0[0] * beta, v0[1] * beta);
                k0.y = pkrtz(v0[2] * beta, v0[3] * beta);
                k0.z = pkrtz(v1[0] * beta, v1[1] * beta);
                k0.w = pkrtz(v1[2] * beta, v1[3] * beta);
                k1.x = pkrtz(v0[4] * beta, v0[5] * beta);
                k1.y = pkrtz(v0[6] * beta, v0[7] * beta);
                k1.z = pkrtz(v1[4] * beta, v1[5] * beta);
                k1.w = pkrtz(v1[6] * beta, v1[7] * beta);
                *(uint4*)&KbP[0][r0] = k0;
                *(uint4*)&KbP[1][r0] = k1;
#pragma unroll
                for (int c = 0; c < 8; ++c)
                    *(unsigned*)&VtH[c][r0] = pkrtz(v0[c], v1[c]);
            }
            __syncthreads();

            // ---------------- MFMA: swapped QK^T, fp16 ----------------
            const int qbase = chunk * 64 + qtile * 32;
            FragU qfB;
            {
                uint2 qh = KbP[h][qbase + ln];
                qfB.u[0] = qh.x; qfB.u[1] = qh.y; qfB.u[2] = qh.x; qfB.u[3] = qh.y;
            }
            f32x16 zc;
#pragma unroll
            for (int i = 0; i < 16; ++i) zc[i] = 0.f;
            f32x16 accA = zc, accB = zc;

#pragma unroll 2
            for (int t = 0; t < 8; ++t) {
                const int kbase = ((qu << 3) | t) << 5;
                FragU kfA;
                {
                    uint2 kh = KbP[h][kbase + ln];
                    kfA.u[0] = kh.x; kfA.u[1] = kh.y; kfA.u[2] = 0; kfA.u[3] = 0;
                }
                f32x16 s = __builtin_amdgcn_mfma_f32_32x32x16_f16(kfA.s, qfB.s, zc, 0, 0, 0);
                float p[16];
#pragma unroll
                for (int g = 0; g < 16; ++g) p[g] = exp2f(s[g]);

                FragU a1, a2;
#pragma unroll
                for (int vi = 0; vi < 4; ++vi) {
                    a1.u[vi] = pkrtz(p[2 * vi], p[2 * vi + 1]);
                    a2.u[vi] = pkrtz(p[8 + 2 * vi], p[8 + 2 * vi + 1]);
                }
                FragU v1h, v2h;
                if (ln < 8) {
                    const unsigned* q0 = (const unsigned*)&VtH[ln][kbase + 4 * h];
                    const unsigned* q1 = (const unsigned*)&VtH[ln][kbase + 8 + 4 * h];
                    const unsigned* q2 = (const unsigned*)&VtH[ln][kbase + 16 + 4 * h];
                    const unsigned* q3 = (const unsigned*)&VtH[ln][kbase + 24 + 4 * h];
                    v1h.u[0] = q0[0]; v1h.u[1] = q0[1]; v1h.u[2] = q1[0]; v1h.u[3] = q1[1];
                    v2h.u[0] = q2[0]; v2h.u[1] = q2[1]; v2h.u[2] = q3[0]; v2h.u[3] = q3[1];
                } else if (ln == 8) {
#pragma unroll
                    for (int i = 0; i < 4; ++i) { v1h.u[i] = 0x3C003C00u; v2h.u[i] = 0x3C003C00u; }
                } else {
#pragma unroll
                    for (int i = 0; i < 4; ++i) { v1h.u[i] = 0; v2h.u[i] = 0; }
                }
                accA = __builtin_amdgcn_mfma_f32_32x32x16_f16(a1.s, v1h.s, accA, 0, 0, 0);
                accB = __builtin_amdgcn_mfma_f32_32x32x16_f16(a2.s, v2h.s, accB, 0, 0, 0);
            }

            if (ln <= 8) {
#pragma unroll
                for (int g = 0; g < 16; ++g)
                    Olds[w][(g & 3) + 8 * (g >> 2) + 4 * h][ln] = accA[g] + accB[g];
            }
            __syncthreads();

            // ---- epilogue by wave `ph` (concurrent with next phase's stage) ----
            if ((tid >> 6) == ph) {
                const int r = tid & 63;
                const int rr = r & 31;
                const int w0 = (r >> 5) * 4;
                float o[9];
#pragma unroll
                for (int c = 0; c < 9; ++c)
                    o[c] = (Olds[w0][rr][c] + Olds[w0 + 1][rr][c])
                         + (Olds[w0 + 2][rr][c] + Olds[w0 + 3][rr][c]);
                float inv = 1.0f / o[8];
                float outv[8];
#pragma unroll
                for (int c = 0; c < 8; ++c) outv[c] = o[c] * inv;

                const float* W  = attn_w + l * 64; const float* Wb  = attn_b + l * 8;
                const float* g1 = ln1_g + l * 8;   const float* b1v = ln1_b + l * 8;
                const float* W1 = ffn_w1 + l * 64; const float* c1  = ffn_b1 + l * 8;
                const float* W2 = ffn_w2 + l * 64; const float* c2  = ffn_b2 + l * 8;
                const float* g2 = ln2_g + l * 8;   const float* b2v = ln2_b + l * 8;

                float xv[8];
#pragma unroll
                for (int j = 0; j < 8; ++j) xv[j] = x_lds[ph][r][j];

                float y[8]; float m = 0.f;
#pragma unroll
                for (int j = 0; j < 8; ++j) {
                    float vv = Wb[j];
#pragma unroll
                    for (int i = 0; i < 8; ++i) vv += outv[i] * W[i * 8 + j];
                    y[j] = xv[j] + vv;
                    m += y[j];
                }
                m *= 0.125f;
                float var = 0.f;
#pragma unroll
                for (int j = 0; j < 8; ++j) { float dd = y[j] - m; var += dd * dd; }
                var *= 0.125f;
                float rsg = rsqrtf(var + LNEPS);
                float xn[8];
#pragma unroll
                for (int j = 0; j < 8; ++j) xn[j] = g1[j] * (y[j] - m) * rsg + b1v[j];

                float hh[8];
#pragma unroll
                for (int j = 0; j < 8; ++j) {
                    float vv = c1[j];
#pragma unroll
                    for (int i = 0; i < 8; ++i) vv += xn[i] * W1[i * 8 + j];
                    hh[j] = vv;
                }
                float qff[8]; qhead(hh, qff);
                float m2 = 0.f;
#pragma unroll
                for (int j = 0; j < 8; ++j) {
                    float vv = c2[j];
#pragma unroll
                    for (int i = 0; i < 8; ++i) vv += qff[i] * W2[i * 8 + j];
                    y[j] = xn[j] + vv;
                    m2 += y[j];
                }
                m2 *= 0.125f;
                float var2 = 0.f;
#pragma unroll
                for (int j = 0; j < 8; ++j) { float dd = y[j] - m2; var2 += dd * dd; }
                var2 *= 0.125f;
                float rs2 = rsqrtf(var2 + LNEPS);
#pragma unroll
                for (int j = 0; j < 8; ++j) {
                    float xo = g2[j] * (y[j] - m2) * rs2 + b2v[j];
                    x_lds[ph][r][j] = xo;
                    xv[j] = xo;
                }

                if (l < 5) {
                    float z[8]; qhead(xv, z);
                    f32x4 z0 = {z[0], z[1], z[2], z[3]}, z1 = {z[4], z[5], z[6], z[7]};
                    llc_store_row(qw + ((long)bb * SEQ + chunk * 64 + r) * 8, z0, z1);
                    // wave-level release: vmcnt covers all 64 lanes' stores
                    asm volatile("s_waitcnt vmcnt(0)" ::: "memory");
                    if (r == 0) sys_store_u32(&flags[F(l + 1, bb, chunk)], 1u);
                }
            }
            // no barrier: next stage's KbP writes ordered by Olds barrier;
            // this epilogue's Olds reads ordered before next MFMA by next
            // phase's post-stage barrier.
        }
    }

    // ---------------- pool + classifier (per phase, fence-free) ----------------
    if ((tid >> 6) < 2) {
        const int ph = tid >> 6;
        const int r = tid & 63;
        const int bb = group * 2 + ph;
        float a[8];
#pragma unroll
        for (int j = 0; j < 8; ++j) {
            a[j] = x_lds[ph][r][j];
#pragma unroll
            for (int off = 1; off <= 32; off <<= 1) a[j] += __shfl_xor(a[j], off);
        }
        if (r < 8) sys_store(&partial[(bb * 16 + chunk) * 8 + r], a[r]);
    }
    asm volatile("s_waitcnt vmcnt(0)" ::: "memory");
    __syncthreads();
    if (tid == 0) {
        unsigned r = __hip_atomic_fetch_add(&pcnt[(group * 2) * 16], 1u,
                                            __ATOMIC_RELAXED, __HIP_MEMORY_SCOPE_AGENT);
        isL[0] = (r == 15u);
    }
    if (tid == 64) {
        unsigned r = __hip_atomic_fetch_add(&pcnt[(group * 2 + 1) * 16], 1u,
                                            __ATOMIC_RELAXED, __HIP_MEMORY_SCOPE_AGENT);
        isL[1] = (r == 15u);
    }
    __syncthreads();
    if ((tid >> 6) < 2) {
        const int ph = tid >> 6;
        if (isL[ph]) {
            const int bb = group * 2 + ph;
            const int lr = tid & 63;
            int g = lr >> 3, j = lr & 7;
            float s = sys_load(&partial[(bb * 16 + g) * 8 + j])
                    + sys_load(&partial[(bb * 16 + g + 8) * 8 + j]);
            s += __shfl_xor(s, 8); s += __shfl_xor(s, 16); s += __shfl_xor(s, 32);
            float poolj = s * (1.0f / 1024.0f);
            int c = lr < 10 ? lr : 9;
            float o = cls_b[c];
#pragma unroll
            for (int j2 = 0; j2 < 8; ++j2)
                o += __shfl(poolj, j2) * cls_w[j2 * 10 + c];
            if (lr < 10) out[bb * 10 + lr] = o;
        }
    }
}

extern "C" void kernel_launch(void* const* d_in, const int* in_sizes, int n_in,
                              void* d_out, int out_size, void* d_ws, size_t ws_size,
                              hipStream_t stream) {
    const int*   tokens = (const int*)d_in[0];
    const float* emb    = (const float*)d_in[1];
    const float* ln1_g  = (const float*)d_in[2];
    const float* ln1_b  = (const float*)d_in[3];
    const float* ln2_g  = (const float*)d_in[4];
    const float* ln2_b  = (const float*)d_in[5];
    const float* attn_w = (const float*)d_in[6];
    const float* attn_b = (const float*)d_in[7];
    const float* ffn_w1 = (const float*)d_in[8];
    const float* ffn_b1 = (const float*)d_in[9];
    const float* ffn_w2 = (const float*)d_in[10];
    const float* ffn_b2 = (const float*)d_in[11];
    const float* cls_w  = (const float*)d_in[12];
    const float* cls_b  = (const float*)d_in[13];

    // ws (f32 words): flags 3072 | pcnt 512 | partial 4096 | qkv0 1MB | qkv1 1MB
    unsigned* flags   = (unsigned*)d_ws;
    unsigned* pcnt    = flags + 3072;
    float*    partial = (float*)d_ws + 3584;
    float*    qkv0    = (float*)d_ws + 3584 + 4096;
    float*    qkv1    = qkv0 + (long)NROWS * 8;
    float*    outp    = (float*)d_out;

    zero_flags<<<1, 1024, 0, stream>>>(flags);   // zeroes flags + pcnt
    qt_fused<<<256, 512, 0, stream>>>(
        tokens, emb, attn_w, attn_b, ln1_g, ln1_b,
        ffn_w1, ffn_b1, ffn_w2, ffn_b2, ln2_g, ln2_b,
        cls_w, cls_b, qkv0, qkv1, flags, pcnt, partial, outp);
}